// Round 5
// baseline (134.808 us; speedup 1.0000x reference)
//
#include <hip/hip_runtime.h>

#define NB 32
#define NT 512
#define NC 96                     // float4 per frame (D = 384)
#define NFRAMES 2048              // T * MAX_DUR
#define SLICES 32                 // blocks per batch row
#define FPS (NFRAMES / SLICES)    // 64 frames per slice
#define ITERS (FPS * NC / NT)     // 12 float4 per thread
#define NWAVES (NT / 64)          // 8

typedef float f4 __attribute__((ext_vector_type(4)));

// One block per (row, slice). Wave-shfl scan of the row's durations, binary
// search the slice's frame->source map, then one fully-batched branch-free
// float4 copy (12 loads in flight) with nontemporal stores.
__global__ __launch_bounds__(NT) void lr_fused_kernel(const int* __restrict__ ds,
                                                      const f4* __restrict__ xs,
                                                      f4* __restrict__ out) {
    __shared__ int cum[NT];
    __shared__ int wsum[NWAVES];
    __shared__ int sidx[FPS];
    const int t = threadIdx.x;
    const int lane = t & 63;
    const int w = t >> 6;
    const int slice = blockIdx.x;
    const int b = blockIdx.y;

    // ---- inclusive scan: shfl within wave, then wave-sum combine ----
    int s = ds[b * NT + t];
    #pragma unroll
    for (int off = 1; off < 64; off <<= 1) {
        int u = __shfl_up(s, off);
        if (lane >= off) s += u;
    }
    if (lane == 63) wsum[w] = s;
    __syncthreads();
    int woff = 0, tot = 0;
    #pragma unroll
    for (int i = 0; i < NWAVES; ++i) {
        const int v = wsum[i];
        woff += (i < w) ? v : 0;
        tot += v;
    }
    int total = tot;
    if (total == 0) {                 // all-zero row -> every duration = 1
        cum[t] = t + 1;
        total = NT;
    } else {
        cum[t] = s + woff;
    }
    __syncthreads();

    // ---- frame -> source index for this slice (upper_bound in LDS) ----
    if (t < FPS) {
        const int p = slice * FPS + t;
        int j = -1;
        if (p < total) {
            int lo = 0, hi = NT;      // smallest idx with cum[idx] > p
            while (lo < hi) {
                const int mid = (lo + hi) >> 1;
                if (cum[mid] > p) hi = mid; else lo = mid + 1;
            }
            j = lo;                   // < NT guaranteed (cum[NT-1] = total > p)
        }
        sidx[t] = j;
    }
    __syncthreads();

    // ---- single batched branch-free copy: 12 float4 in flight ----
    const f4* __restrict__ xrow = xs + (size_t)b * NT * NC;
    f4* __restrict__ orow = out + ((size_t)b * NFRAMES + (size_t)slice * FPS) * NC;
    f4 v[ITERS];
    int neg[ITERS];
    #pragma unroll
    for (int u = 0; u < ITERS; ++u) {
        const int e = u * NT + t;
        const int fr = e / NC;            // magic-mul div by 96
        const int c = e - fr * NC;
        const int j = sidx[fr];           // broadcast within wave
        neg[u] = (j < 0);
        const int jj = (j < 0) ? 0 : j;   // always-valid address
        v[u] = xrow[jj * NC + c];         // unconditional load -> batched
    }
    #pragma unroll
    for (int u = 0; u < ITERS; ++u) {
        const int e = u * NT + t;
        f4 r = neg[u] ? (f4)(0.f) : v[u];
        __builtin_nontemporal_store(r, &orow[e]);   // streaming store
    }
}

extern "C" void kernel_launch(void* const* d_in, const int* in_sizes, int n_in,
                              void* d_out, int out_size, void* d_ws, size_t ws_size,
                              hipStream_t stream) {
    const float* xs = (const float*)d_in[0];
    const int*   ds = (const int*)d_in[1];
    float* out = (float*)d_out;
    (void)in_sizes; (void)n_in; (void)out_size; (void)d_ws; (void)ws_size;

    dim3 grid(SLICES, NB);
    lr_fused_kernel<<<grid, NT, 0, stream>>>(ds, (const f4*)xs, (f4*)out);
}

// Round 7
// 132.208 us; speedup vs baseline: 1.0197x; 1.0197x over previous
//
#include <hip/hip_runtime.h>

#define NB 32
#define NT 512
#define NC 96                     // float4 per frame (D = 384)
#define NFRAMES 2048              // T * MAX_DUR
#define SLICES 64                 // blocks per batch row
#define FPS (NFRAMES / SLICES)    // 32 frames per slice
#define ITERS (FPS * NC / NT)     // 6 float4 per thread
#define NWAVES (NT / 64)          // 8

typedef float f4 __attribute__((ext_vector_type(4)));

// One block per (row, slice). Wave-shfl scan of the row's durations, binary
// search the slice's frame->source map, then a batched branch-free float4
// copy (6 in flight) with nontemporal stores. __launch_bounds__(512,8)
// pins VGPR<=64 -> 32 waves/CU.
__global__ __launch_bounds__(NT, 8) void lr_fused_kernel(const int* __restrict__ ds,
                                                         const f4* __restrict__ xs,
                                                         f4* __restrict__ out) {
    __shared__ int cum[NT];
    __shared__ int wsum[NWAVES];
    __shared__ int sidx[FPS];
    const int t = threadIdx.x;
    const int lane = t & 63;
    const int w = t >> 6;
    const int slice = blockIdx.x;
    const int b = blockIdx.y;

    // ---- inclusive scan: shfl within wave, then wave-sum combine ----
    int s = ds[b * NT + t];
    #pragma unroll
    for (int off = 1; off < 64; off <<= 1) {
        int u = __shfl_up(s, off);
        if (lane >= off) s += u;
    }
    if (lane == 63) wsum[w] = s;
    __syncthreads();
    int woff = 0, tot = 0;
    #pragma unroll
    for (int i = 0; i < NWAVES; ++i) {
        const int v = wsum[i];
        woff += (i < w) ? v : 0;
        tot += v;
    }
    int total = tot;
    if (total == 0) {                 // all-zero row -> every duration = 1
        cum[t] = t + 1;
        total = NT;
    } else {
        cum[t] = s + woff;
    }
    __syncthreads();

    // ---- frame -> source index for this slice (upper_bound in LDS) ----
    if (t < FPS) {
        const int p = slice * FPS + t;
        int j = -1;
        if (p < total) {
            int lo = 0, hi = NT;      // smallest idx with cum[idx] > p
            while (lo < hi) {
                const int mid = (lo + hi) >> 1;
                if (cum[mid] > p) hi = mid; else lo = mid + 1;
            }
            j = lo;                   // < NT guaranteed (cum[NT-1] = total > p)
        }
        sidx[t] = j;
    }
    __syncthreads();

    // ---- batched branch-free copy: 6 float4 in flight ----
    const f4* __restrict__ xrow = xs + (size_t)b * NT * NC;
    f4* __restrict__ orow = out + ((size_t)b * NFRAMES + (size_t)slice * FPS) * NC;
    f4 v[ITERS];
    int neg[ITERS];
    #pragma unroll
    for (int u = 0; u < ITERS; ++u) {
        const int e = u * NT + t;
        const int fr = e / NC;            // magic-mul div by 96
        const int c = e - fr * NC;
        const int j = sidx[fr];           // broadcast within wave
        neg[u] = (j < 0);
        const int jj = (j < 0) ? 0 : j;   // always-valid address
        v[u] = xrow[jj * NC + c];         // unconditional load -> batched
    }
    #pragma unroll
    for (int u = 0; u < ITERS; ++u) {
        const int e = u * NT + t;
        f4 r = neg[u] ? (f4)(0.f) : v[u];
        __builtin_nontemporal_store(r, &orow[e]);   // streaming store
    }
}

extern "C" void kernel_launch(void* const* d_in, const int* in_sizes, int n_in,
                              void* d_out, int out_size, void* d_ws, size_t ws_size,
                              hipStream_t stream) {
    const float* xs = (const float*)d_in[0];
    const int*   ds = (const int*)d_in[1];
    float* out = (float*)d_out;
    (void)in_sizes; (void)n_in; (void)out_size; (void)d_ws; (void)ws_size;

    dim3 grid(SLICES, NB);
    lr_fused_kernel<<<grid, NT, 0, stream>>>(ds, (const f4*)xs, (f4*)out);
}